// Round 3
// baseline (304.977 us; speedup 1.0000x reference)
//
#include <hip/hip_runtime.h>
#include <hip/hip_bf16.h>

typedef __bf16 bf16;
typedef __attribute__((ext_vector_type(8))) __bf16 bf16x8;
typedef __attribute__((ext_vector_type(4))) float f32x4;

#define EMB 768
#define T_SEQ 1024
#define HEADS 12
#define HDIM 64

// ---------------- elementwise fp32 -> bf16 (8 el/thread) ----------------
__global__ void cvt_f32_bf16_k(const float* __restrict__ in, bf16* __restrict__ out, int n8) {
  const int i = blockIdx.x * 256 + threadIdx.x;
  if (i < n8) {
    const float4* p = (const float4*)(in + (size_t)i * 8);
    const float4 a = p[0], b = p[1];
    bf16x8 v;
    v[0] = (bf16)a.x; v[1] = (bf16)a.y; v[2] = (bf16)a.z; v[3] = (bf16)a.w;
    v[4] = (bf16)b.x; v[5] = (bf16)b.y; v[6] = (bf16)b.z; v[7] = (bf16)b.w;
    *(bf16x8*)(out + (size_t)i * 8) = v;
  }
}

// ---------------- transpose + convert: in fp32 [R][C] -> out bf16 [C][R] ----------------
__global__ void transpose_cvt_k(const float* __restrict__ in, bf16* __restrict__ out, int R, int C) {
  __shared__ float tile[32][33];
  const int c0 = blockIdx.x * 32, r0 = blockIdx.y * 32;
  const int tx = threadIdx.x, ty = threadIdx.y;
  for (int i = ty; i < 32; i += 8)
    tile[i][tx] = in[(size_t)(r0 + i) * C + c0 + tx];
  __syncthreads();
  for (int i = ty; i < 32; i += 8)
    out[(size_t)(c0 + i) * R + r0 + tx] = (bf16)tile[tx][i];
}

// ---------------- GEMM: C[M][N] = A[M][K] @ Bt[N][K]^T + bias (fp32 bias/acc) ----------------
// MODE 0: QKV epilogue (bf16 stores) — cols [0,1536) -> Cb (ld 1536); cols [1536,2304) -> Vtg[B,H,d,T]
// MODE 1: fp32 row-major store to Cf (ld = N)
template <int MODE>
__global__ __launch_bounds__(256) void gemm_bt(
    const bf16* __restrict__ A, const bf16* __restrict__ Bt, const float* __restrict__ bias,
    bf16* __restrict__ Cb, bf16* __restrict__ Vtg, float* __restrict__ Cf,
    int M, int N, int K, int ldc) {
  __shared__ __align__(16) bf16 As[128 * 32];
  __shared__ __align__(16) bf16 Bs[128 * 32];
  const int lane = threadIdx.x & 63;
  const int wave = threadIdx.x >> 6;
  const int quad = lane >> 4, lc = lane & 15;
  const int m0 = blockIdx.y * 128, n0 = blockIdx.x * 128;
  const int wm = (wave >> 1) * 64, wn = (wave & 1) * 64;
  const int srow = lane >> 2;        // 0..15 (row within 16-row chunk)
  const int skk = (lane & 3) * 8;    // 0,8,16,24 (k offset)

  f32x4 zero = {0.f, 0.f, 0.f, 0.f};
  f32x4 acc[4][4];
#pragma unroll
  for (int i = 0; i < 4; ++i)
#pragma unroll
    for (int j = 0; j < 4; ++j) acc[i][j] = zero;

  for (int k0 = 0; k0 < K; k0 += 32) {
    __syncthreads();
#pragma unroll
    for (int c = wave; c < 8; c += 4) {
      const bf16* gA = A + (size_t)(m0 + c * 16 + srow) * K + k0 + skk;
      const bf16* gB = Bt + (size_t)(n0 + c * 16 + srow) * K + k0 + skk;
      __builtin_amdgcn_global_load_lds((const __attribute__((address_space(1))) void*)gA,
                                       (__attribute__((address_space(3))) void*)(As + c * 512), 16, 0, 0);
      __builtin_amdgcn_global_load_lds((const __attribute__((address_space(1))) void*)gB,
                                       (__attribute__((address_space(3))) void*)(Bs + c * 512), 16, 0, 0);
    }
    __syncthreads();
    bf16x8 af[4], bfr[4];
#pragma unroll
    for (int t = 0; t < 4; ++t) af[t] = *(const bf16x8*)&As[(wm + t * 16 + lc) * 32 + quad * 8];
#pragma unroll
    for (int t = 0; t < 4; ++t) bfr[t] = *(const bf16x8*)&Bs[(wn + t * 16 + lc) * 32 + quad * 8];
#pragma unroll
    for (int tm = 0; tm < 4; ++tm)
#pragma unroll
      for (int tn = 0; tn < 4; ++tn)
        acc[tm][tn] = __builtin_amdgcn_mfma_f32_16x16x32_bf16(af[tm], bfr[tn], acc[tm][tn], 0, 0, 0);
  }

#pragma unroll
  for (int tm = 0; tm < 4; ++tm) {
#pragma unroll
    for (int tn = 0; tn < 4; ++tn) {
      const int col = n0 + wn + tn * 16 + lc;
      const float bv = bias[col];
#pragma unroll
      for (int r = 0; r < 4; ++r) {
        const int row = m0 + wm + tm * 16 + quad * 4 + r;
        const float v = acc[tm][tn][r] + bv;
        if (MODE == 0) {
          if (col < 2 * EMB) {
            Cb[(size_t)row * ldc + col] = (bf16)v;
          } else {
            const int cc = col - 2 * EMB;
            const int h = cc >> 6, dd = cc & 63;
            const int b = row >> 10, t = row & 1023;
            Vtg[(((size_t)(b * HEADS + h) * HDIM + dd) << 10) + t] = (bf16)v;
          }
        } else {
          Cf[(size_t)row * ldc + col] = v;
        }
      }
    }
  }
}

// ---------------- causal flash attention (all-bf16 internal) ----------------
// qk: [B*T][1536] (Q cols 0..767, K cols 768..1535); vtg: [B,H,64,1024]; outb: [B*T][768]
__global__ __launch_bounds__(256) void attn_k(const bf16* __restrict__ qk, const bf16* __restrict__ vtg,
                                              bf16* __restrict__ outb) {
  __shared__ __align__(16) bf16 Qs[64][72];    // row stride 144B (16B aligned, 2-way banks)
  __shared__ __align__(16) bf16 Ks[128][72];
  __shared__ __align__(16) bf16 Vt[64][136];   // V^T: [d][key], stride 272B
  __shared__ __align__(16) bf16 Ps[64][136];   // P:   [q][key]

  const int lane = threadIdx.x & 63;
  const int wave = threadIdx.x >> 6;
  const int quad = lane >> 4, lc = lane & 15;
  const int qt = blockIdx.x;            // q-tile (64 rows)
  const int bh = blockIdx.y;            // b*HEADS + h
  const int h = bh % HEADS;
  const int b = bh / HEADS;
  const int q0 = qt * 64;
  const size_t rowB = (size_t)b * T_SEQ;
  const int hoff = h * HDIM;

  // stage Q tile once
  for (int c = threadIdx.x; c < 64 * 8; c += 256) {
    const int r = c >> 3, d8 = (c & 7) * 8;
    const bf16* g = qk + (rowB + q0 + r) * (2 * EMB) + hoff + d8;
    *(bf16x8*)&Qs[r][d8] = *(const bf16x8*)g;
  }

  f32x4 zero = {0.f, 0.f, 0.f, 0.f};
  float m_run[4], l_run[4];
  f32x4 o[4];
#pragma unroll
  for (int r = 0; r < 4; ++r) { m_run[r] = -1e30f; l_run[r] = 0.f; }
#pragma unroll
  for (int dt = 0; dt < 4; ++dt) o[dt] = zero;

  const int nkt = (q0 >> 7) + 1;  // causal: only K-tiles with keys <= q0+63
  for (int kt = 0; kt < nkt; ++kt) {
    const int kb = kt * 128;
    __syncthreads();
    // stage K tile [128 keys][64 d]
    for (int c = threadIdx.x; c < 128 * 8; c += 256) {
      const int key = c >> 3, d8 = (c & 7) * 8;
      const bf16* g = qk + (rowB + kb + key) * (2 * EMB) + EMB + hoff + d8;
      *(bf16x8*)&Ks[key][d8] = *(const bf16x8*)g;
    }
    // stage V^T tile [64 d][128 keys] (already transposed in global)
    for (int c = threadIdx.x; c < 64 * 16; c += 256) {
      const int dd = c >> 4, kc = (c & 15) * 8;
      const bf16* g = vtg + (((size_t)bh * HDIM + dd) << 10) + kb + kc;
      *(bf16x8*)&Vt[dd][kc] = *(const bf16x8*)g;
    }
    __syncthreads();

    // S = Q @ K^T for this wave's 16 q-rows x 128 keys
    f32x4 s[8];
#pragma unroll
    for (int j = 0; j < 8; ++j) s[j] = zero;
#pragma unroll
    for (int ks = 0; ks < 2; ++ks) {
      bf16x8 aq = *(const bf16x8*)&Qs[wave * 16 + lc][ks * 32 + quad * 8];
#pragma unroll
      for (int j = 0; j < 8; ++j) {
        bf16x8 bk = *(const bf16x8*)&Ks[j * 16 + lc][ks * 32 + quad * 8];
        s[j] = __builtin_amdgcn_mfma_f32_16x16x32_bf16(aq, bk, s[j], 0, 0, 0);
      }
    }

    const bool last = (kt == nkt - 1);
    float mt[4];
#pragma unroll
    for (int r = 0; r < 4; ++r) mt[r] = -1e30f;
#pragma unroll
    for (int j = 0; j < 8; ++j) {
#pragma unroll
      for (int r = 0; r < 4; ++r) {
        float v = s[j][r] * 0.125f;  // 1/sqrt(64)
        if (last) {
          const int qg = q0 + wave * 16 + quad * 4 + r;
          const int kg = kb + j * 16 + lc;
          if (kg > qg) v = -1e30f;
        }
        s[j][r] = v;
        mt[r] = fmaxf(mt[r], v);
      }
    }
#pragma unroll
    for (int off = 1; off < 16; off <<= 1)
#pragma unroll
      for (int r = 0; r < 4; ++r) mt[r] = fmaxf(mt[r], __shfl_xor(mt[r], off));

    float alpha[4], rs[4];
#pragma unroll
    for (int r = 0; r < 4; ++r) {
      const float mn = fmaxf(m_run[r], mt[r]);
      alpha[r] = __expf(m_run[r] - mn);
      m_run[r] = mn;
      rs[r] = 0.f;
    }
    // P = exp(S - m) -> LDS in A-operand layout (cross-lane: barrier below before read)
#pragma unroll
    for (int j = 0; j < 8; ++j) {
#pragma unroll
      for (int r = 0; r < 4; ++r) {
        const float p = __expf(s[j][r] - m_run[r]);
        rs[r] += p;
        Ps[wave * 16 + quad * 4 + r][j * 16 + lc] = (bf16)p;
      }
    }
#pragma unroll
    for (int off = 1; off < 16; off <<= 1)
#pragma unroll
      for (int r = 0; r < 4; ++r) rs[r] += __shfl_xor(rs[r], off);
#pragma unroll
    for (int r = 0; r < 4; ++r) l_run[r] = l_run[r] * alpha[r] + rs[r];
#pragma unroll
    for (int dt = 0; dt < 4; ++dt)
#pragma unroll
      for (int r = 0; r < 4; ++r) o[dt][r] *= alpha[r];

    __syncthreads();  // make Ps writes visible across lanes

    // O += P @ V  (A = P rows from LDS, B = V^T rows -> contiguous k)
#pragma unroll
    for (int ks = 0; ks < 4; ++ks) {
      bf16x8 ap = *(const bf16x8*)&Ps[wave * 16 + lc][ks * 32 + quad * 8];
#pragma unroll
      for (int dt = 0; dt < 4; ++dt) {
        bf16x8 bv = *(const bf16x8*)&Vt[dt * 16 + lc][ks * 32 + quad * 8];
        o[dt] = __builtin_amdgcn_mfma_f32_16x16x32_bf16(ap, bv, o[dt], 0, 0, 0);
      }
    }
  }

  // epilogue: out[b*T + q][h*64 + d] = O / l
#pragma unroll
  for (int r = 0; r < 4; ++r) {
    const float inv = 1.0f / l_run[r];
    const size_t row = rowB + q0 + wave * 16 + quad * 4 + r;
#pragma unroll
    for (int dt = 0; dt < 4; ++dt)
      outb[row * EMB + hoff + dt * 16 + lc] = (bf16)(o[dt][r] * inv);
  }
}

// ---------------- launch ----------------
extern "C" void kernel_launch(void* const* d_in, const int* in_sizes, int n_in,
                              void* d_out, int out_size, void* d_ws, size_t ws_size,
                              hipStream_t stream) {
  const float* x = (const float*)d_in[0];      // [M][768] fp32
  const float* Wattn = (const float*)d_in[1];  // [768][2304] fp32
  const float* battn = (const float*)d_in[2];  // [2304] fp32
  const float* Wproj = (const float*)d_in[3];  // [768][768] fp32
  const float* bproj = (const float*)d_in[4];  // [768] fp32
  float* out = (float*)d_out;                  // [M][768] fp32

  const int M = in_sizes[0] / EMB;  // 8192
  const int Bn = M / T_SEQ;         // 8

  bf16* ws = (bf16*)d_ws;
  bf16* xb = ws;                                        // [M][768] bf16
  bf16* Wt_attn = xb + (size_t)M * EMB;                 // [2304][768]
  bf16* Wt_proj = Wt_attn + (size_t)3 * EMB * EMB;      // [768][768]
  bf16* qkbuf = Wt_proj + (size_t)EMB * EMB;            // [M][1536]
  bf16* vtg = qkbuf + (size_t)M * 2 * EMB;              // [B,H,64,1024]
  bf16* attnb = vtg + (size_t)M * EMB;                  // [M][768]

  const int n8 = M * EMB / 8;
  cvt_f32_bf16_k<<<(n8 + 255) / 256, 256, 0, stream>>>(x, xb, n8);
  transpose_cvt_k<<<dim3(3 * EMB / 32, EMB / 32), dim3(32, 8), 0, stream>>>(
      Wattn, Wt_attn, EMB, 3 * EMB);
  transpose_cvt_k<<<dim3(EMB / 32, EMB / 32), dim3(32, 8), 0, stream>>>(
      Wproj, Wt_proj, EMB, EMB);

  gemm_bt<0><<<dim3(3 * EMB / 128, M / 128), 256, 0, stream>>>(
      xb, Wt_attn, battn, qkbuf, vtg, nullptr, M, 3 * EMB, EMB, 2 * EMB);

  attn_k<<<dim3(T_SEQ / 64, Bn * HEADS), 256, 0, stream>>>(qkbuf, vtg, attnb);

  gemm_bt<1><<<dim3(EMB / 128, M / 128), 256, 0, stream>>>(
      attnb, Wt_proj, bproj, nullptr, nullptr, out, M, EMB, EMB, EMB);
}

// Round 4
// 219.375 us; speedup vs baseline: 1.3902x; 1.3902x over previous
//
#include <hip/hip_runtime.h>
#include <hip/hip_bf16.h>

typedef __bf16 bf16;
typedef __attribute__((ext_vector_type(8))) __bf16 bf16x8;
typedef __attribute__((ext_vector_type(4))) short s16x4;
typedef __attribute__((ext_vector_type(4))) float f32x4;

#define EMB 768
#define T_SEQ 1024
#define HEADS 12
#define HDIM 64

// ---------------- elementwise fp32 -> bf16 (8 el/thread) ----------------
__global__ void cvt_f32_bf16_k(const float* __restrict__ in, bf16* __restrict__ out, int n8) {
  const int i = blockIdx.x * 256 + threadIdx.x;
  if (i < n8) {
    const float4* p = (const float4*)(in + (size_t)i * 8);
    const float4 a = p[0], b = p[1];
    bf16x8 v;
    v[0] = (bf16)a.x; v[1] = (bf16)a.y; v[2] = (bf16)a.z; v[3] = (bf16)a.w;
    v[4] = (bf16)b.x; v[5] = (bf16)b.y; v[6] = (bf16)b.z; v[7] = (bf16)b.w;
    *(bf16x8*)(out + (size_t)i * 8) = v;
  }
}

// ---------------- transpose + convert: in fp32 [R][C] -> out bf16 [C][R] ----------------
__global__ void transpose_cvt_k(const float* __restrict__ in, bf16* __restrict__ out, int R, int C) {
  __shared__ float tile[32][33];
  const int c0 = blockIdx.x * 32, r0 = blockIdx.y * 32;
  const int tx = threadIdx.x, ty = threadIdx.y;
  for (int i = ty; i < 32; i += 8)
    tile[i][tx] = in[(size_t)(r0 + i) * C + c0 + tx];
  __syncthreads();
  for (int i = ty; i < 32; i += 8)
    out[(size_t)(c0 + i) * R + r0 + tx] = (bf16)tile[tx][i];
}

// ---------------- GEMM: C[M][N] = A[M][K] @ Bt[N][K]^T + bias (fp32 bias/acc) ----------------
// MODE 0: QKV epilogue (bf16 stores) — cols [0,1536) -> Cb (ld 1536); cols [1536,2304) -> Vtg[B,H,d,T]
// MODE 1: fp32 row-major store to Cf (ld = N)
template <int MODE>
__global__ __launch_bounds__(256) void gemm_bt(
    const bf16* __restrict__ A, const bf16* __restrict__ Bt, const float* __restrict__ bias,
    bf16* __restrict__ Cb, bf16* __restrict__ Vtg, float* __restrict__ Cf,
    int M, int N, int K, int ldc) {
  __shared__ __align__(16) bf16 As[128 * 32];
  __shared__ __align__(16) bf16 Bs[128 * 32];
  const int lane = threadIdx.x & 63;
  const int wave = threadIdx.x >> 6;
  const int quad = lane >> 4, lc = lane & 15;
  const int m0 = blockIdx.y * 128, n0 = blockIdx.x * 128;
  const int wm = (wave >> 1) * 64, wn = (wave & 1) * 64;
  const int srow = lane >> 2;        // 0..15 (row within 16-row chunk)
  const int skk = (lane & 3) * 8;    // 0,8,16,24 (k offset)

  f32x4 zero = {0.f, 0.f, 0.f, 0.f};
  f32x4 acc[4][4];
#pragma unroll
  for (int i = 0; i < 4; ++i)
#pragma unroll
    for (int j = 0; j < 4; ++j) acc[i][j] = zero;

  for (int k0 = 0; k0 < K; k0 += 32) {
    __syncthreads();
#pragma unroll
    for (int c = wave; c < 8; c += 4) {
      const bf16* gA = A + (size_t)(m0 + c * 16 + srow) * K + k0 + skk;
      const bf16* gB = Bt + (size_t)(n0 + c * 16 + srow) * K + k0 + skk;
      __builtin_amdgcn_global_load_lds((const __attribute__((address_space(1))) void*)gA,
                                       (__attribute__((address_space(3))) void*)(As + c * 512), 16, 0, 0);
      __builtin_amdgcn_global_load_lds((const __attribute__((address_space(1))) void*)gB,
                                       (__attribute__((address_space(3))) void*)(Bs + c * 512), 16, 0, 0);
    }
    __syncthreads();
    bf16x8 af[4], bfr[4];
#pragma unroll
    for (int t = 0; t < 4; ++t) af[t] = *(const bf16x8*)&As[(wm + t * 16 + lc) * 32 + quad * 8];
#pragma unroll
    for (int t = 0; t < 4; ++t) bfr[t] = *(const bf16x8*)&Bs[(wn + t * 16 + lc) * 32 + quad * 8];
#pragma unroll
    for (int tm = 0; tm < 4; ++tm)
#pragma unroll
      for (int tn = 0; tn < 4; ++tn)
        acc[tm][tn] = __builtin_amdgcn_mfma_f32_16x16x32_bf16(af[tm], bfr[tn], acc[tm][tn], 0, 0, 0);
  }

#pragma unroll
  for (int tm = 0; tm < 4; ++tm) {
#pragma unroll
    for (int tn = 0; tn < 4; ++tn) {
      const int col = n0 + wn + tn * 16 + lc;
      const float bv = bias[col];
#pragma unroll
      for (int r = 0; r < 4; ++r) {
        const int row = m0 + wm + tm * 16 + quad * 4 + r;
        const float v = acc[tm][tn][r] + bv;
        if (MODE == 0) {
          if (col < 2 * EMB) {
            Cb[(size_t)row * ldc + col] = (bf16)v;
          } else {
            const int cc = col - 2 * EMB;
            const int h = cc >> 6, dd = cc & 63;
            const int b = row >> 10, t = row & 1023;
            Vtg[(((size_t)(b * HEADS + h) * HDIM + dd) << 10) + t] = (bf16)v;
          }
        } else {
          Cf[(size_t)row * ldc + col] = v;
        }
      }
    }
  }
}

// ---------------- causal flash attention, transposed-score form ----------------
// S' = K·Q^T comes out with q in lanes (col=lc) and keys in regs (row=quad*4+r),
// which IS the B-operand layout of mfma_16x16x16 — so P never touches LDS.
// qk: [B*T][1536] (Q cols 0..767, K cols 768..1535); vtg: [B,H,64,1024]; outb: [B*T][768]
__global__ __launch_bounds__(512, 4) void attn_k(const bf16* __restrict__ qk,
                                                 const bf16* __restrict__ vtg,
                                                 bf16* __restrict__ outb) {
  __shared__ __align__(16) bf16 Qs[128][72];   // Q tile [q][d], stride 144B; reused for O out
  __shared__ __align__(16) bf16 Ks[128][72];   // K tile [key][d]
  __shared__ __align__(16) bf16 Vt[64][136];   // V^T tile [d][key]

  const int lane = threadIdx.x & 63;
  const int wave = threadIdx.x >> 6;           // 0..7, each owns 16 q rows
  const int quad = lane >> 4, lc = lane & 15;
  // 1-D grid: bh fastest (96 = 0 mod 8 -> all q-tiles of one head share an XCD),
  // qt reversed so heavy diagonal blocks dispatch first.
  const int flat = blockIdx.x;
  const int bh = flat % (HEADS * 8);
  const int qt = 7 - flat / (HEADS * 8);
  const int h = bh % HEADS;
  const int b = bh / HEADS;
  const int q0 = qt * 128;
  const size_t rowB = (size_t)b * T_SEQ;
  const int hoff = h * HDIM;
  const int tid = threadIdx.x;

  // stage Q tile once: 128 rows x 64 d
  for (int c = tid; c < 128 * 8; c += 512) {
    const int r = c >> 3, d8 = (c & 7) * 8;
    *(bf16x8*)&Qs[r][d8] = *(const bf16x8*)(qk + (rowB + q0 + r) * (2 * EMB) + hoff + d8);
  }

  f32x4 zero = {0.f, 0.f, 0.f, 0.f};
  float m_run = -1e30f, l_run = 0.f;
  f32x4 o[4];  // O'[d][q]: col q=lc, row d=dt*16+quad*4+r
#pragma unroll
  for (int dt = 0; dt < 4; ++dt) o[dt] = zero;
  const int myq = q0 + wave * 16 + lc;

  for (int kt = 0; kt <= qt; ++kt) {
    const int kb = kt * 128;
    __syncthreads();
    for (int c = tid; c < 128 * 8; c += 512) {
      const int key = c >> 3, d8 = (c & 7) * 8;
      *(bf16x8*)&Ks[key][d8] =
          *(const bf16x8*)(qk + (rowB + kb + key) * (2 * EMB) + EMB + hoff + d8);
    }
    for (int c = tid; c < 64 * 16; c += 512) {
      const int dd = c >> 4, kc = (c & 15) * 8;
      *(bf16x8*)&Vt[dd][kc] =
          *(const bf16x8*)(vtg + (((size_t)bh * HDIM + dd) << 10) + kb + kc);
    }
    __syncthreads();

    // S'[key][q] = sum_d K[key][d] Q[q][d] : A = K frag, B = Q frag
    f32x4 s[8];
#pragma unroll
    for (int j = 0; j < 8; ++j) s[j] = zero;
#pragma unroll
    for (int ks = 0; ks < 2; ++ks) {
      bf16x8 bq = *(const bf16x8*)&Qs[wave * 16 + lc][ks * 32 + quad * 8];
#pragma unroll
      for (int j = 0; j < 8; ++j) {
        bf16x8 ak = *(const bf16x8*)&Ks[j * 16 + lc][ks * 32 + quad * 8];
        s[j] = __builtin_amdgcn_mfma_f32_16x16x32_bf16(ak, bq, s[j], 0, 0, 0);
      }
    }

    // scale + causal mask (diagonal tile only) + per-q max (q = lane's lc)
    const bool diag = (kt == qt);
    float mloc = -1e30f;
#pragma unroll
    for (int j = 0; j < 8; ++j) {
#pragma unroll
      for (int r = 0; r < 4; ++r) {
        float v = s[j][r] * 0.125f;  // 1/sqrt(64)
        if (diag && (kb + j * 16 + quad * 4 + r > myq)) v = -1e30f;
        s[j][r] = v;
        mloc = fmaxf(mloc, v);
      }
    }
    mloc = fmaxf(mloc, __shfl_xor(mloc, 16));
    mloc = fmaxf(mloc, __shfl_xor(mloc, 32));

    const float mnew = fmaxf(m_run, mloc);
    const float alpha = __expf(m_run - mnew);
    m_run = mnew;

    // P = exp(S'-m): stays in registers as 16x16x16 B-operand frags
    s16x4 pf[8];
    float rsum = 0.f;
#pragma unroll
    for (int j = 0; j < 8; ++j) {
#pragma unroll
      for (int r = 0; r < 4; ++r) {
        const float p = __expf(s[j][r] - mnew);
        rsum += p;
        pf[j][r] = __builtin_bit_cast(short, (bf16)p);
      }
    }
    rsum += __shfl_xor(rsum, 16);
    rsum += __shfl_xor(rsum, 32);
    l_run = l_run * alpha + rsum;
#pragma unroll
    for (int dt = 0; dt < 4; ++dt)
#pragma unroll
      for (int r = 0; r < 4; ++r) o[dt][r] *= alpha;

    // O'[d][q] += V^T-frag (A) · P-frag (B), K=16 per step
#pragma unroll
    for (int j = 0; j < 8; ++j) {
#pragma unroll
      for (int dt = 0; dt < 4; ++dt) {
        s16x4 av = *(const s16x4*)&Vt[dt * 16 + lc][j * 16 + quad * 4];
        o[dt] = __builtin_amdgcn_mfma_f32_16x16x16bf16_1k(av, pf[j], o[dt], 0, 0, 0);
      }
    }
  }

  // epilogue: normalize, transpose O' through Qs (dead), coalesced store
  const float inv = 1.0f / l_run;
  __syncthreads();  // all waves done reading Qs/Ks/Vt
#pragma unroll
  for (int dt = 0; dt < 4; ++dt)
#pragma unroll
    for (int r = 0; r < 4; ++r)
      Qs[wave * 16 + lc][dt * 16 + quad * 4 + r] = (bf16)(o[dt][r] * inv);
  __syncthreads();
  for (int c = tid; c < 128 * 8; c += 512) {
    const int r = c >> 3, d8 = (c & 7) * 8;
    *(bf16x8*)(outb + (rowB + q0 + r) * EMB + hoff + d8) = *(const bf16x8*)&Qs[r][d8];
  }
}

// ---------------- launch ----------------
extern "C" void kernel_launch(void* const* d_in, const int* in_sizes, int n_in,
                              void* d_out, int out_size, void* d_ws, size_t ws_size,
                              hipStream_t stream) {
  const float* x = (const float*)d_in[0];      // [M][768] fp32
  const float* Wattn = (const float*)d_in[1];  // [768][2304] fp32
  const float* battn = (const float*)d_in[2];  // [2304] fp32
  const float* Wproj = (const float*)d_in[3];  // [768][768] fp32
  const float* bproj = (const float*)d_in[4];  // [768] fp32
  float* out = (float*)d_out;                  // [M][768] fp32

  const int M = in_sizes[0] / EMB;  // 8192
  const int Bn = M / T_SEQ;         // 8

  bf16* ws = (bf16*)d_ws;
  bf16* xb = ws;                                        // [M][768] bf16
  bf16* Wt_attn = xb + (size_t)M * EMB;                 // [2304][768]
  bf16* Wt_proj = Wt_attn + (size_t)3 * EMB * EMB;      // [768][768]
  bf16* qkbuf = Wt_proj + (size_t)EMB * EMB;            // [M][1536]
  bf16* vtg = qkbuf + (size_t)M * 2 * EMB;              // [B,H,64,1024]
  bf16* attnb = vtg + (size_t)M * EMB;                  // [M][768]

  const int n8 = M * EMB / 8;
  cvt_f32_bf16_k<<<(n8 + 255) / 256, 256, 0, stream>>>(x, xb, n8);
  transpose_cvt_k<<<dim3(3 * EMB / 32, EMB / 32), dim3(32, 8), 0, stream>>>(
      Wattn, Wt_attn, EMB, 3 * EMB);
  transpose_cvt_k<<<dim3(EMB / 32, EMB / 32), dim3(32, 8), 0, stream>>>(
      Wproj, Wt_proj, EMB, EMB);

  gemm_bt<0><<<dim3(3 * EMB / 128, M / 128), 256, 0, stream>>>(
      xb, Wt_attn, battn, qkbuf, vtg, nullptr, M, 3 * EMB, EMB, 2 * EMB);

  attn_k<<<dim3((T_SEQ / 128) * Bn * HEADS), 512, 0, stream>>>(qkbuf, vtg, attnb);

  gemm_bt<1><<<dim3(EMB / 128, M / 128), 256, 0, stream>>>(
      attnb, Wt_proj, bproj, nullptr, nullptr, out, M, EMB, EMB, EMB);
}

// Round 5
// 181.168 us; speedup vs baseline: 1.6834x; 1.2109x over previous
//
#include <hip/hip_runtime.h>
#include <hip/hip_bf16.h>

typedef __bf16 bf16;
typedef __attribute__((ext_vector_type(8))) __bf16 bf16x8;
typedef __attribute__((ext_vector_type(4))) short s16x4;
typedef __attribute__((ext_vector_type(4))) float f32x4;

#define EMB 768
#define T_SEQ 1024
#define HEADS 12
#define HDIM 64

// ---------------- fused prep: x fp32->bf16, W_attn / W_proj transpose+cvt ----------------
// grid = [0,3072): cvt x (8 el/thread) | [3072,4800): W_attn 32x32 tiles | [4800,5376): W_proj
__global__ void prep_k(const float* __restrict__ x, bf16* __restrict__ xb,
                       const float* __restrict__ Wa, bf16* __restrict__ Wta,
                       const float* __restrict__ Wp, bf16* __restrict__ Wtp) {
  __shared__ float tile[32][33];
  const int blk = blockIdx.x, tid = threadIdx.x;
  if (blk < 3072) {
    const size_t i = (size_t)blk * 256 + tid;
    const float4* p = (const float4*)(x + i * 8);
    const float4 a = p[0], b = p[1];
    bf16x8 v;
    v[0] = (bf16)a.x; v[1] = (bf16)a.y; v[2] = (bf16)a.z; v[3] = (bf16)a.w;
    v[4] = (bf16)b.x; v[5] = (bf16)b.y; v[6] = (bf16)b.z; v[7] = (bf16)b.w;
    *(bf16x8*)(xb + i * 8) = v;
    return;
  }
  const float* in;
  bf16* out;
  int C, t;
  if (blk < 3072 + 1728) { in = Wa; out = Wta; C = 3 * EMB; t = blk - 3072; }
  else                   { in = Wp; out = Wtp; C = EMB;     t = blk - 4800; }
  const int R = EMB;
  const int c0 = (t % (C / 32)) * 32, r0 = (t / (C / 32)) * 32;
  const int tx = tid & 31, ty = tid >> 5;
  for (int i = ty; i < 32; i += 8)
    tile[i][tx] = in[(size_t)(r0 + i) * C + c0 + tx];
  __syncthreads();
  for (int i = ty; i < 32; i += 8)
    out[(size_t)(c0 + i) * R + r0 + tx] = (bf16)tile[tx][i];
}

// ---------------- GEMM: C[M][N] = A[M][K] @ Bt[N][K]^T + bias, BK=64 (2x32 slices) ----------------
// MODE 0: bf16 row-major store; MODE 1: fp32 row-major store
template <int MODE>
__global__ __launch_bounds__(256) void gemm_bt(
    const bf16* __restrict__ A, const bf16* __restrict__ Bt, const float* __restrict__ bias,
    bf16* __restrict__ Cb, float* __restrict__ Cf, int M, int N, int K) {
  __shared__ __align__(16) bf16 As0[128 * 32];
  __shared__ __align__(16) bf16 As1[128 * 32];
  __shared__ __align__(16) bf16 Bs0[128 * 32];
  __shared__ __align__(16) bf16 Bs1[128 * 32];
  const int lane = threadIdx.x & 63;
  const int wave = threadIdx.x >> 6;
  const int quad = lane >> 4, lc = lane & 15;
  const int m0 = blockIdx.y * 128, n0 = blockIdx.x * 128;
  const int wm = (wave >> 1) * 64, wn = (wave & 1) * 64;
  const int srow = lane >> 2;        // 0..15 (row within 16-row chunk)
  const int skk = (lane & 3) * 8;    // 0,8,16,24 (k offset within slice)

  f32x4 zero = {0.f, 0.f, 0.f, 0.f};
  f32x4 acc[4][4];
#pragma unroll
  for (int i = 0; i < 4; ++i)
#pragma unroll
    for (int j = 0; j < 4; ++j) acc[i][j] = zero;

  for (int k0 = 0; k0 < K; k0 += 64) {
    __syncthreads();
#pragma unroll
    for (int c = wave; c < 8; c += 4) {
      const bf16* gA = A + (size_t)(m0 + c * 16 + srow) * K + k0 + skk;
      const bf16* gB = Bt + (size_t)(n0 + c * 16 + srow) * K + k0 + skk;
      __builtin_amdgcn_global_load_lds((const __attribute__((address_space(1))) void*)gA,
                                       (__attribute__((address_space(3))) void*)(As0 + c * 512), 16, 0, 0);
      __builtin_amdgcn_global_load_lds((const __attribute__((address_space(1))) void*)(gA + 32),
                                       (__attribute__((address_space(3))) void*)(As1 + c * 512), 16, 0, 0);
      __builtin_amdgcn_global_load_lds((const __attribute__((address_space(1))) void*)gB,
                                       (__attribute__((address_space(3))) void*)(Bs0 + c * 512), 16, 0, 0);
      __builtin_amdgcn_global_load_lds((const __attribute__((address_space(1))) void*)(gB + 32),
                                       (__attribute__((address_space(3))) void*)(Bs1 + c * 512), 16, 0, 0);
    }
    __syncthreads();
    {
      bf16x8 af[4], bfr[4];
#pragma unroll
      for (int t = 0; t < 4; ++t) af[t] = *(const bf16x8*)&As0[(wm + t * 16 + lc) * 32 + quad * 8];
#pragma unroll
      for (int t = 0; t < 4; ++t) bfr[t] = *(const bf16x8*)&Bs0[(wn + t * 16 + lc) * 32 + quad * 8];
#pragma unroll
      for (int tm = 0; tm < 4; ++tm)
#pragma unroll
        for (int tn = 0; tn < 4; ++tn)
          acc[tm][tn] = __builtin_amdgcn_mfma_f32_16x16x32_bf16(af[tm], bfr[tn], acc[tm][tn], 0, 0, 0);
    }
    {
      bf16x8 af[4], bfr[4];
#pragma unroll
      for (int t = 0; t < 4; ++t) af[t] = *(const bf16x8*)&As1[(wm + t * 16 + lc) * 32 + quad * 8];
#pragma unroll
      for (int t = 0; t < 4; ++t) bfr[t] = *(const bf16x8*)&Bs1[(wn + t * 16 + lc) * 32 + quad * 8];
#pragma unroll
      for (int tm = 0; tm < 4; ++tm)
#pragma unroll
        for (int tn = 0; tn < 4; ++tn)
          acc[tm][tn] = __builtin_amdgcn_mfma_f32_16x16x32_bf16(af[tm], bfr[tn], acc[tm][tn], 0, 0, 0);
    }
  }

#pragma unroll
  for (int tm = 0; tm < 4; ++tm) {
#pragma unroll
    for (int tn = 0; tn < 4; ++tn) {
      const int col = n0 + wn + tn * 16 + lc;
      const float bv = bias[col];
#pragma unroll
      for (int r = 0; r < 4; ++r) {
        const int row = m0 + wm + tm * 16 + quad * 4 + r;
        const float v = acc[tm][tn][r] + bv;
        if (MODE == 0) Cb[(size_t)row * N + col] = (bf16)v;
        else           Cf[(size_t)row * N + col] = v;
      }
    }
  }
}

// ---------------- causal flash attention, transposed-score form ----------------
// qkv: [B*T][2304] rows (q|k|v); V transposed into LDS during staging; outb: [B*T][768]
__global__ __launch_bounds__(512, 4) void attn_k(const bf16* __restrict__ qkv,
                                                 bf16* __restrict__ outb) {
  __shared__ __align__(16) bf16 Qs[128][72];   // [q][d], stride 144B; reused for O out
  __shared__ __align__(16) bf16 Ks[128][72];   // [key][d]
  __shared__ __align__(16) bf16 Vt[64][132];   // V^T [d][key], stride 264B (8B-aligned b64 frags)

  const int lane = threadIdx.x & 63;
  const int wave = threadIdx.x >> 6;           // 0..7, each owns 16 q rows
  const int quad = lane >> 4, lc = lane & 15;
  const int flat = blockIdx.x;
  const int bh = flat % (HEADS * 8);           // 96 ≡ 0 mod 8: head's q-tiles share an XCD
  const int qt = 7 - flat / (HEADS * 8);       // heavy diagonal blocks first
  const int h = bh % HEADS;
  const int b = bh / HEADS;
  const int q0 = qt * 128;
  const size_t rowB = (size_t)b * T_SEQ;
  const int hoff = h * HDIM;
  const int tid = threadIdx.x;

  // stage Q tile once: 128 rows x 64 d
  for (int c = tid; c < 128 * 8; c += 512) {
    const int r = c >> 3, d8 = (c & 7) * 8;
    *(bf16x8*)&Qs[r][d8] = *(const bf16x8*)(qkv + (rowB + q0 + r) * (3 * EMB) + hoff + d8);
  }

  f32x4 zero = {0.f, 0.f, 0.f, 0.f};
  float m_run = -1e30f, l_run = 0.f;
  f32x4 o[4];  // O'[d][q]: col q=lc, row d=dt*16+quad*4+r
#pragma unroll
  for (int dt = 0; dt < 4; ++dt) o[dt] = zero;
  const int myq = q0 + wave * 16 + lc;

  for (int kt = 0; kt <= qt; ++kt) {
    const int kb = kt * 128;
    __syncthreads();
    for (int c = tid; c < 128 * 8; c += 512) {
      const int key = c >> 3, d8 = (c & 7) * 8;
      *(bf16x8*)&Ks[key][d8] =
          *(const bf16x8*)(qkv + (rowB + kb + key) * (3 * EMB) + EMB + hoff + d8);
    }
    // V: coalesced row read, transposed scalar writes into Vt[d][key]
    for (int c = tid; c < 128 * 8; c += 512) {
      const int key = c >> 3, d8 = (c & 7) * 8;
      bf16x8 v = *(const bf16x8*)(qkv + (rowB + kb + key) * (3 * EMB) + 2 * EMB + hoff + d8);
#pragma unroll
      for (int i = 0; i < 8; ++i) Vt[d8 + i][key] = v[i];
    }
    __syncthreads();

    // S'[key][q] = sum_d K[key][d] Q[q][d] : A = K frag, B = Q frag
    f32x4 s[8];
#pragma unroll
    for (int j = 0; j < 8; ++j) s[j] = zero;
#pragma unroll
    for (int ks = 0; ks < 2; ++ks) {
      bf16x8 bq = *(const bf16x8*)&Qs[wave * 16 + lc][ks * 32 + quad * 8];
#pragma unroll
      for (int j = 0; j < 8; ++j) {
        bf16x8 ak = *(const bf16x8*)&Ks[j * 16 + lc][ks * 32 + quad * 8];
        s[j] = __builtin_amdgcn_mfma_f32_16x16x32_bf16(ak, bq, s[j], 0, 0, 0);
      }
    }

    // scale + causal mask (diagonal tile only) + per-q max (q = lane's lc)
    const bool diag = (kt == qt);
    float mloc = -1e30f;
#pragma unroll
    for (int j = 0; j < 8; ++j) {
#pragma unroll
      for (int r = 0; r < 4; ++r) {
        float v = s[j][r] * 0.125f;  // 1/sqrt(64)
        if (diag && (kb + j * 16 + quad * 4 + r > myq)) v = -1e30f;
        s[j][r] = v;
        mloc = fmaxf(mloc, v);
      }
    }
    mloc = fmaxf(mloc, __shfl_xor(mloc, 16));
    mloc = fmaxf(mloc, __shfl_xor(mloc, 32));

    const float mnew = fmaxf(m_run, mloc);
    const float alpha = __expf(m_run - mnew);
    m_run = mnew;

    // P = exp(S'-m): stays in registers as 16x16x16 B-operand frags
    s16x4 pf[8];
    float rsum = 0.f;
#pragma unroll
    for (int j = 0; j < 8; ++j) {
#pragma unroll
      for (int r = 0; r < 4; ++r) {
        const float p = __expf(s[j][r] - mnew);
        rsum += p;
        pf[j][r] = __builtin_bit_cast(short, (bf16)p);
      }
    }
    rsum += __shfl_xor(rsum, 16);
    rsum += __shfl_xor(rsum, 32);
    l_run = l_run * alpha + rsum;
#pragma unroll
    for (int dt = 0; dt < 4; ++dt)
#pragma unroll
      for (int r = 0; r < 4; ++r) o[dt][r] *= alpha;

    // O'[d][q] += V^T-frag (A) · P-frag (B), K=16 per step
#pragma unroll
    for (int j = 0; j < 8; ++j) {
#pragma unroll
      for (int dt = 0; dt < 4; ++dt) {
        s16x4 av = *(const s16x4*)&Vt[dt * 16 + lc][j * 16 + quad * 4];
        o[dt] = __builtin_amdgcn_mfma_f32_16x16x16bf16_1k(av, pf[j], o[dt], 0, 0, 0);
      }
    }
  }

  // epilogue: normalize, transpose O' through Qs (dead), coalesced store
  const float inv = 1.0f / l_run;
  __syncthreads();  // all waves done reading Qs/Ks/Vt
#pragma unroll
  for (int dt = 0; dt < 4; ++dt)
#pragma unroll
    for (int r = 0; r < 4; ++r)
      Qs[wave * 16 + lc][dt * 16 + quad * 4 + r] = (bf16)(o[dt][r] * inv);
  __syncthreads();
  for (int c = tid; c < 128 * 8; c += 512) {
    const int r = c >> 3, d8 = (c & 7) * 8;
    *(bf16x8*)(outb + (rowB + q0 + r) * EMB + hoff + d8) = *(const bf16x8*)&Qs[r][d8];
  }
}

// ---------------- launch ----------------
extern "C" void kernel_launch(void* const* d_in, const int* in_sizes, int n_in,
                              void* d_out, int out_size, void* d_ws, size_t ws_size,
                              hipStream_t stream) {
  const float* x = (const float*)d_in[0];      // [M][768] fp32
  const float* Wattn = (const float*)d_in[1];  // [768][2304] fp32
  const float* battn = (const float*)d_in[2];  // [2304] fp32
  const float* Wproj = (const float*)d_in[3];  // [768][768] fp32
  const float* bproj = (const float*)d_in[4];  // [768] fp32
  float* out = (float*)d_out;                  // [M][768] fp32

  const int M = in_sizes[0] / EMB;  // 8192
  const int Bn = M / T_SEQ;         // 8

  bf16* ws = (bf16*)d_ws;
  bf16* xb = ws;                                        // [M][768] bf16
  bf16* Wt_attn = xb + (size_t)M * EMB;                 // [2304][768]
  bf16* Wt_proj = Wt_attn + (size_t)3 * EMB * EMB;      // [768][768]
  bf16* qkv = Wt_proj + (size_t)EMB * EMB;              // [M][2304]
  bf16* attnb = qkv + (size_t)M * 3 * EMB;              // [M][768]

  const int cvt_blocks = M * EMB / 8 / 256;             // 3072
  prep_k<<<cvt_blocks + 1728 + 576, 256, 0, stream>>>(x, xb, Wattn, Wt_attn, Wproj, Wt_proj);

  gemm_bt<0><<<dim3(3 * EMB / 128, M / 128), 256, 0, stream>>>(
      xb, Wt_attn, battn, qkv, nullptr, M, 3 * EMB, EMB);

  attn_k<<<dim3((T_SEQ / 128) * Bn * HEADS), 512, 0, stream>>>(qkv, attnb);

  gemm_bt<1><<<dim3(EMB / 128, M / 128), 256, 0, stream>>>(
      attnb, Wt_proj, bproj, nullptr, out, M, EMB, EMB);
}